// Round 4
// baseline (270.738 us; speedup 1.0000x reference)
//
#include <hip/hip_runtime.h>
#include <stdint.h>

#define OUT_F   2048
#define IN_BASE 2048
#define N_EMB   64
#define IN_TOT  2176   // 2048 + 128
#define NNZ_W   400000
#define NNZ_B   1024
#define BATCH   8192

#define KBLKS   (IN_TOT / 16)   // 136
#define MBLKS   (BATCH / 32)    // 256
#define NBLKS   (OUT_F / 32)    // 64

typedef __bf16 bf16x8 __attribute__((ext_vector_type(8)));
typedef __bf16 bf16x4 __attribute__((ext_vector_type(4)));
typedef float  floatx16 __attribute__((ext_vector_type(16)));

// Fragment-tiled layouts (bf16):
//   A_t[kb][mb][lane][j]: A[mb*32 + (lane&31)][kb*16 + (lane>>5)*8 + j]
//   B_t[kb][nb][lane][j]: W[nb*32 + (lane&31)][kb*16 + (lane>>5)*8 + j]
// One 32x16 fragment = 64 lanes x 16 B = 1 KB contiguous -> GEMM loads are
// single fully-coalesced global_load_dwordx4 per fragment, no LDS needed.

// ---------------------------------------------------------------------------
// Kernel 1: build A_t from x + embed layers, via LDS transpose.
// grid.x = m_blk (256), grid.y = chunk c (17); tile = 32 rows x 128 k.
// ---------------------------------------------------------------------------
__global__ void __launch_bounds__(256) build_xt_kernel(
    const float* __restrict__ x,
    const float* __restrict__ e0v, const int* __restrict__ e0p,
    const float* __restrict__ e1v, const int* __restrict__ e1p,
    __bf16* __restrict__ A_t)
{
    __shared__ __bf16 tile[32 * 136];   // rows padded to 136 elems (272 B)

    const int t  = threadIdx.x;
    const int mb = blockIdx.x;          // 0..255
    const int c  = blockIdx.y;          // 0..16
    const int m0 = mb * 32;

    // phase 1: stage 32x128 (global k = c*128 ..) into LDS as bf16
    {
        const int r  = t >> 3;          // 0..31
        const int cc = t & 7;           // 16-col group
        __bf16* dst = tile + r * 136 + cc * 16;
        if (c < 16) {
            const float* src = x + (size_t)(m0 + r) * IN_BASE + c * 128 + cc * 16;
#pragma unroll
            for (int q = 0; q < 4; q++) {
                float4 v = *(const float4*)(src + q * 4);
                bf16x4 o;
                o[0] = (__bf16)v.x; o[1] = (__bf16)v.y;
                o[2] = (__bf16)v.z; o[3] = (__bf16)v.w;
                *(bf16x4*)(dst + q * 4) = o;
            }
        } else {
            const float* xr = x + (size_t)(m0 + r) * IN_BASE;
#pragma unroll
            for (int i = 0; i < 16; i++) {
                int kk = cc * 16 + i;          // 0..127 within embed region
                float val;
                if (kk < N_EMB) {
                    val = e0v[kk] * xr[e0p[kk]];
                } else {
                    int j = kk - N_EMB;
                    int p = e1p[j];
                    float base = (p < IN_BASE) ? xr[p]
                               : e0v[p - IN_BASE] * xr[e0p[p - IN_BASE]];
                    val = e1v[j] * base;
                }
                dst[i] = (__bf16)val;
            }
        }
    }
    __syncthreads();

    // phase 2: emit 8 fragment tiles (k_blk_loc 0..7), coalesced 16B stores
#pragma unroll
    for (int g = 0; g < 2; g++) {
        const int kbl  = g * 4 + (t >> 6);   // 0..7
        const int lane = t & 63;
        const int m    = lane & 31;
        const int kh   = lane >> 5;
        bf16x8 v = *(const bf16x8*)(tile + m * 136 + kbl * 16 + kh * 8);
        const int kb = c * 8 + kbl;          // global k_blk
        *(bf16x8*)(A_t + ((size_t)kb * MBLKS + mb) * 512 + lane * 8) = v;
    }
}

// ---------------------------------------------------------------------------
// Kernel 2: COO scatter-add for W (into fragment-tiled fp32) + bias
// ---------------------------------------------------------------------------
__global__ void __launch_bounds__(256) scatter_kernel(
    const float* __restrict__ wv, const int* __restrict__ wr,
    const int* __restrict__ wc,
    const float* __restrict__ bv, const int* __restrict__ bi,
    float* __restrict__ Wf_t, float* __restrict__ bf)
{
    int i = blockIdx.x * 256 + threadIdx.x;
    if (i < NNZ_W) {
        int r = wr[i], k = wc[i];
        size_t idx = ((size_t)(k >> 4) * NBLKS + (r >> 5)) * 512
                   + ((r & 31) + 32 * ((k >> 3) & 1)) * 8 + (k & 7);
        atomicAdd(Wf_t + idx, wv[i]);
    } else if (i < NNZ_W + NNZ_B) {
        int j = i - NNZ_W;
        atomicAdd(bf + bi[j], bv[j]);
    }
}

// ---------------------------------------------------------------------------
// Kernel 3: tiled W fp32 -> bf16 (elementwise, same layout)
// ---------------------------------------------------------------------------
__global__ void __launch_bounds__(256) w_to_bf16_kernel(
    const float* __restrict__ Wf_t, __bf16* __restrict__ Wb_t)
{
    int e = (blockIdx.x * 256 + threadIdx.x) * 4;
    const float4 v = *(const float4*)(Wf_t + e);
    bf16x4 o;
    o[0] = (__bf16)v.x; o[1] = (__bf16)v.y; o[2] = (__bf16)v.z; o[3] = (__bf16)v.w;
    *(bf16x4*)(Wb_t + e) = o;
}

// ---------------------------------------------------------------------------
// Kernel 4: LDS-free GEMM. Block 128x256 (4 waves 2x2, wave tile 64x128 as
// 2x4 of mfma_f32_32x32x16_bf16). All fragments loaded directly from the
// tiled global layouts: 6 coalesced dwordx4 loads + 8 MFMAs per k_blk,
// software-pipelined 2-deep; NO LDS, NO barriers.
// bn = blockIdx & 7 -> XCD affinity: each XCD's B strip (1.1 MB) fits its L2.
// ---------------------------------------------------------------------------
__global__ void __launch_bounds__(256, 2) gemm_kernel(
    const __bf16* __restrict__ A_t,
    const __bf16* __restrict__ B_t,
    const float*  __restrict__ bias,
    float* __restrict__ C)
{
    const int tid  = threadIdx.x;
    const int bn   = blockIdx.x & 7;    // 0..7  (N tiles of 256)
    const int bm   = blockIdx.x >> 3;   // 0..63 (M tiles of 128)
    const int wave = tid >> 6;
    const int lane = tid & 63;
    const int wr   = wave >> 1;         // 0..1
    const int wc   = wave & 1;          // 0..1
    const int mb0  = bm * 4 + wr * 2;   // first of 2 m_blks
    const int nb0  = bn * 8 + wc * 4;   // first of 4 n_blks

    const __bf16* Ap = A_t + ((size_t)mb0 * 64 + lane) * 8;
    const __bf16* Bp = B_t + ((size_t)nb0 * 64 + lane) * 8;
    const size_t AS = (size_t)MBLKS * 512;   // A_t k_blk stride (elems)
    const size_t BS = (size_t)NBLKS * 512;   // B_t k_blk stride

    floatx16 acc[2][4] = {};
    bf16x8 a0[2], b0[4], a1[2], b1[4];

#define LOADF(ar, br, kb)                                                     \
    {                                                                         \
        const __bf16* ap = Ap + (size_t)(kb) * AS;                            \
        const __bf16* bp = Bp + (size_t)(kb) * BS;                            \
        ar[0] = *(const bf16x8*)(ap);                                         \
        ar[1] = *(const bf16x8*)(ap + 512);                                   \
        br[0] = *(const bf16x8*)(bp);                                         \
        br[1] = *(const bf16x8*)(bp + 512);                                   \
        br[2] = *(const bf16x8*)(bp + 1024);                                  \
        br[3] = *(const bf16x8*)(bp + 1536);                                  \
    }
#define MFMAF(ar, br)                                                         \
    _Pragma("unroll")                                                         \
    for (int mi = 0; mi < 2; mi++)                                            \
        _Pragma("unroll")                                                     \
        for (int ni = 0; ni < 4; ni++)                                        \
            acc[mi][ni] = __builtin_amdgcn_mfma_f32_32x32x16_bf16(            \
                ar[mi], br[ni], acc[mi][ni], 0, 0, 0);

    LOADF(a0, b0, 0)
    for (int i = 0; i < 67; i++) {        // k_blk pairs: 0..133
        LOADF(a1, b1, 2 * i + 1)
        MFMAF(a0, b0)
        LOADF(a0, b0, 2 * i + 2)          // 2i+2 <= 134, in bounds
        MFMAF(a1, b1)
    }
    LOADF(a1, b1, 135)
    MFMAF(a0, b0)                         // kb = 134
    MFMAF(a1, b1)                         // kb = 135

    // epilogue: C/D col = lane&31, row = (reg&3) + 8*(reg>>2) + 4*(lane>>5)
    const int l32 = lane & 31;
    const int kh  = lane >> 5;
#pragma unroll
    for (int mi = 0; mi < 2; mi++) {
        const int rowb = bm * 128 + wr * 64 + mi * 32 + 4 * kh;
#pragma unroll
        for (int ni = 0; ni < 4; ni++) {
            const int colg = bn * 256 + wc * 128 + ni * 32 + l32;
            const float bvv = bias[colg];
#pragma unroll
            for (int reg = 0; reg < 16; reg++) {
                const int rowg = rowb + (reg & 3) + 8 * (reg >> 2);
                C[(size_t)rowg * OUT_F + colg] = acc[mi][ni][reg] + bvv;
            }
        }
    }
#undef LOADF
#undef MFMAF
}

// ---------------------------------------------------------------------------
// Launch
// ---------------------------------------------------------------------------
extern "C" void kernel_launch(void* const* d_in, const int* in_sizes, int n_in,
                              void* d_out, int out_size, void* d_ws, size_t ws_size,
                              hipStream_t stream) {
    const float* x      = (const float*)d_in[0];
    const float* w_vals = (const float*)d_in[1];
    const int*   w_rows = (const int*)  d_in[2];
    const int*   w_cols = (const int*)  d_in[3];
    const float* b_vals = (const float*)d_in[4];
    const int*   b_idx  = (const int*)  d_in[5];
    const float* e0v    = (const float*)d_in[6];
    const int*   e0p    = (const int*)  d_in[7];
    const float* e1v    = (const float*)d_in[8];
    const int*   e1p    = (const int*)  d_in[9];
    float* out = (float*)d_out;

    // ws: Wf_t fp32 | bias fp32 (contiguous memset) | Wb_t bf16 | A_t bf16
    char* ws = (char*)d_ws;
    const size_t W_F32_BYTES  = (size_t)OUT_F * IN_TOT * 4;   // 17,825,792
    const size_t B_F32_BYTES  = (size_t)OUT_F * 4;
    const size_t W_BF16_BYTES = (size_t)OUT_F * IN_TOT * 2;   //  8,912,896
    float*  Wf_t = (float*)ws;
    float*  bf   = (float*)(ws + W_F32_BYTES);
    __bf16* Wb_t = (__bf16*)(ws + W_F32_BYTES + B_F32_BYTES);
    __bf16* A_t  = (__bf16*)(ws + W_F32_BYTES + B_F32_BYTES + W_BF16_BYTES);

    hipMemsetAsync(Wf_t, 0, W_F32_BYTES + B_F32_BYTES, stream);

    dim3 bxg(MBLKS, 17);
    build_xt_kernel<<<bxg, 256, 0, stream>>>(x, e0v, e0p, e1v, e1p, A_t);

    scatter_kernel<<<(NNZ_W + NNZ_B + 255) / 256, 256, 0, stream>>>(
        w_vals, w_rows, w_cols, b_vals, b_idx, Wf_t, bf);

    w_to_bf16_kernel<<<((size_t)OUT_F * IN_TOT / 4) / 256, 256, 0, stream>>>(Wf_t, Wb_t);

    gemm_kernel<<<512, 256, 0, stream>>>(A_t, Wb_t, bf, out);
}

// Round 5
// 265.611 us; speedup vs baseline: 1.0193x; 1.0193x over previous
//
#include <hip/hip_runtime.h>
#include <stdint.h>

#define OUT_F   2048
#define IN_BASE 2048
#define N_EMB   64
#define IN_TOT  2176   // 2048 + 128
#define NNZ_W   400000
#define NNZ_B   1024
#define BATCH   8192

#define KBLKS   (IN_TOT / 16)   // 136
#define MBLKS   (BATCH / 32)    // 256
#define NBLKS   (OUT_F / 32)    // 64

typedef __bf16 bf16x8 __attribute__((ext_vector_type(8)));
typedef __bf16 bf16x4 __attribute__((ext_vector_type(4)));
typedef float  floatx16 __attribute__((ext_vector_type(16)));

// Fragment-tiled layouts (bf16):
//   A_t[kb][mb][lane][j]: A[mb*32 + (lane&31)][kb*16 + (lane>>5)*8 + j]
//   B_t[kb][nb][lane][j]: W[nb*32 + (lane&31)][kb*16 + (lane>>5)*8 + j]
// One 32x16 fragment = 64 lanes x 16 B = 1 KB contiguous -> GEMM loads are
// single fully-coalesced global_load_dwordx4 per fragment, no LDS needed.

// ---------------------------------------------------------------------------
// Kernel 1: build A_t from x + embed layers, via LDS transpose.
// ---------------------------------------------------------------------------
__global__ void __launch_bounds__(256) build_xt_kernel(
    const float* __restrict__ x,
    const float* __restrict__ e0v, const int* __restrict__ e0p,
    const float* __restrict__ e1v, const int* __restrict__ e1p,
    __bf16* __restrict__ A_t)
{
    __shared__ __bf16 tile[32 * 136];   // rows padded to 136 elems

    const int t  = threadIdx.x;
    const int mb = blockIdx.x;          // 0..255
    const int c  = blockIdx.y;          // 0..16
    const int m0 = mb * 32;

    {
        const int r  = t >> 3;          // 0..31
        const int cc = t & 7;           // 16-col group
        __bf16* dst = tile + r * 136 + cc * 16;
        if (c < 16) {
            const float* src = x + (size_t)(m0 + r) * IN_BASE + c * 128 + cc * 16;
#pragma unroll
            for (int q = 0; q < 4; q++) {
                float4 v = *(const float4*)(src + q * 4);
                bf16x4 o;
                o[0] = (__bf16)v.x; o[1] = (__bf16)v.y;
                o[2] = (__bf16)v.z; o[3] = (__bf16)v.w;
                *(bf16x4*)(dst + q * 4) = o;
            }
        } else {
            const float* xr = x + (size_t)(m0 + r) * IN_BASE;
#pragma unroll
            for (int i = 0; i < 16; i++) {
                int kk = cc * 16 + i;
                float val;
                if (kk < N_EMB) {
                    val = e0v[kk] * xr[e0p[kk]];
                } else {
                    int j = kk - N_EMB;
                    int p = e1p[j];
                    float base = (p < IN_BASE) ? xr[p]
                               : e0v[p - IN_BASE] * xr[e0p[p - IN_BASE]];
                    val = e1v[j] * base;
                }
                dst[i] = (__bf16)val;
            }
        }
    }
    __syncthreads();

#pragma unroll
    for (int g = 0; g < 2; g++) {
        const int kbl  = g * 4 + (t >> 6);   // 0..7
        const int lane = t & 63;
        const int m    = lane & 31;
        const int kh   = lane >> 5;
        bf16x8 v = *(const bf16x8*)(tile + m * 136 + kbl * 16 + kh * 8);
        const int kb = c * 8 + kbl;
        *(bf16x8*)(A_t + ((size_t)kb * MBLKS + mb) * 512 + lane * 8) = v;
    }
}

// ---------------------------------------------------------------------------
// Kernel 2: COO scatter-add for W (fragment-tiled fp32) + bias
// ---------------------------------------------------------------------------
__global__ void __launch_bounds__(256) scatter_kernel(
    const float* __restrict__ wv, const int* __restrict__ wr,
    const int* __restrict__ wc,
    const float* __restrict__ bv, const int* __restrict__ bi,
    float* __restrict__ Wf_t, float* __restrict__ bf)
{
    int i = blockIdx.x * 256 + threadIdx.x;
    if (i < NNZ_W) {
        int r = wr[i], k = wc[i];
        size_t idx = ((size_t)(k >> 4) * NBLKS + (r >> 5)) * 512
                   + ((r & 31) + 32 * ((k >> 3) & 1)) * 8 + (k & 7);
        atomicAdd(Wf_t + idx, wv[i]);
    } else if (i < NNZ_W + NNZ_B) {
        int j = i - NNZ_W;
        atomicAdd(bf + bi[j], bv[j]);
    }
}

// ---------------------------------------------------------------------------
// Kernel 3: tiled W fp32 -> bf16
// ---------------------------------------------------------------------------
__global__ void __launch_bounds__(256) w_to_bf16_kernel(
    const float* __restrict__ Wf_t, __bf16* __restrict__ Wb_t)
{
    int e = (blockIdx.x * 256 + threadIdx.x) * 4;
    const float4 v = *(const float4*)(Wf_t + e);
    bf16x4 o;
    o[0] = (__bf16)v.x; o[1] = (__bf16)v.y; o[2] = (__bf16)v.z; o[3] = (__bf16)v.w;
    *(bf16x4*)(Wb_t + e) = o;
}

// ---------------------------------------------------------------------------
// Kernel 4: LDS-free GEMM, 3-stage software pipeline.
// Block 128x256 (4 waves 2x2, wave tile 64x128 as 2x4 of 32x32x16 MFMA).
// Per k_blk: 6 coalesced dwordx4 loads + 8 MFMAs. 3 buffer stages give each
// wave 3 load-groups in flight (~192 cyc cover); 2 waves/SIMD co-resident
// (launch_bounds(256,2): 128 VGPR + 128 acc AGPR fits 2 waves/EU exactly).
// ---------------------------------------------------------------------------
__global__ void __launch_bounds__(256, 2) gemm_kernel(
    const __bf16* __restrict__ A_t,
    const __bf16* __restrict__ B_t,
    const float*  __restrict__ bias,
    float* __restrict__ C)
{
    const int tid  = threadIdx.x;
    const int bn   = blockIdx.x & 7;    // 0..7  (N tiles of 256)
    const int bm   = blockIdx.x >> 3;   // 0..63 (M tiles of 128)
    const int wave = tid >> 6;
    const int lane = tid & 63;
    const int wr   = wave >> 1;         // 0..1
    const int wc   = wave & 1;          // 0..1
    const int mb0  = bm * 4 + wr * 2;   // first of 2 m_blks
    const int nb0  = bn * 8 + wc * 4;   // first of 4 n_blks

    const __bf16* Ap = A_t + ((size_t)mb0 * 64 + lane) * 8;
    const __bf16* Bp = B_t + ((size_t)nb0 * 64 + lane) * 8;
    const size_t AS = (size_t)MBLKS * 512;   // k_blk stride (elems)
    const size_t BS = (size_t)NBLKS * 512;

    floatx16 acc[2][4] = {};
    bf16x8 a0[2], b0[4], a1[2], b1[4], a2[2], b2[4];

#define LOADF(ar, br, kb)                                                     \
    {                                                                         \
        const __bf16* ap = Ap + (size_t)(kb) * AS;                            \
        const __bf16* bp = Bp + (size_t)(kb) * BS;                            \
        ar[0] = *(const bf16x8*)(ap);                                         \
        ar[1] = *(const bf16x8*)(ap + 512);                                   \
        br[0] = *(const bf16x8*)(bp);                                         \
        br[1] = *(const bf16x8*)(bp + 512);                                   \
        br[2] = *(const bf16x8*)(bp + 1024);                                  \
        br[3] = *(const bf16x8*)(bp + 1536);                                  \
    }
#define MFMAF(ar, br)                                                         \
    _Pragma("unroll")                                                         \
    for (int mi = 0; mi < 2; mi++)                                            \
        _Pragma("unroll")                                                     \
        for (int ni = 0; ni < 4; ni++)                                        \
            acc[mi][ni] = __builtin_amdgcn_mfma_f32_32x32x16_bf16(            \
                ar[mi], br[ni], acc[mi][ni], 0, 0, 0);

    LOADF(a0, b0, 0)
    LOADF(a1, b1, 1)
    LOADF(a2, b2, 2)
    // 44 iters consume kb 0..131, load kb 3..134 (rotation keeps distance 3)
    for (int i = 0; i < 44; i++) {
        const int kb = 3 * i + 3;
        MFMAF(a0, b0) LOADF(a0, b0, kb)
        MFMAF(a1, b1) LOADF(a1, b1, kb + 1)
        MFMAF(a2, b2) LOADF(a2, b2, kb + 2)
    }
    // buffers now hold kb 132,133,134
    MFMAF(a0, b0) LOADF(a0, b0, 135)
    MFMAF(a1, b1)
    MFMAF(a2, b2)
    MFMAF(a0, b0)

    // epilogue: C/D col = lane&31, row = (reg&3) + 8*(reg>>2) + 4*(lane>>5)
    const int l32 = lane & 31;
    const int kh  = lane >> 5;
#pragma unroll
    for (int mi = 0; mi < 2; mi++) {
        const int rowb = bm * 128 + wr * 64 + mi * 32 + 4 * kh;
#pragma unroll
        for (int ni = 0; ni < 4; ni++) {
            const int colg = bn * 256 + wc * 128 + ni * 32 + l32;
            const float bvv = bias[colg];
#pragma unroll
            for (int reg = 0; reg < 16; reg++) {
                const int rowg = rowb + (reg & 3) + 8 * (reg >> 2);
                C[(size_t)rowg * OUT_F + colg] = acc[mi][ni][reg] + bvv;
            }
        }
    }
#undef LOADF
#undef MFMAF
}

// ---------------------------------------------------------------------------
// Launch
// ---------------------------------------------------------------------------
extern "C" void kernel_launch(void* const* d_in, const int* in_sizes, int n_in,
                              void* d_out, int out_size, void* d_ws, size_t ws_size,
                              hipStream_t stream) {
    const float* x      = (const float*)d_in[0];
    const float* w_vals = (const float*)d_in[1];
    const int*   w_rows = (const int*)  d_in[2];
    const int*   w_cols = (const int*)  d_in[3];
    const float* b_vals = (const float*)d_in[4];
    const int*   b_idx  = (const int*)  d_in[5];
    const float* e0v    = (const float*)d_in[6];
    const int*   e0p    = (const int*)  d_in[7];
    const float* e1v    = (const float*)d_in[8];
    const int*   e1p    = (const int*)  d_in[9];
    float* out = (float*)d_out;

    // ws: Wf_t fp32 | bias fp32 (contiguous memset) | Wb_t bf16 | A_t bf16
    char* ws = (char*)d_ws;
    const size_t W_F32_BYTES  = (size_t)OUT_F * IN_TOT * 4;
    const size_t B_F32_BYTES  = (size_t)OUT_F * 4;
    const size_t W_BF16_BYTES = (size_t)OUT_F * IN_TOT * 2;
    float*  Wf_t = (float*)ws;
    float*  bf   = (float*)(ws + W_F32_BYTES);
    __bf16* Wb_t = (__bf16*)(ws + W_F32_BYTES + B_F32_BYTES);
    __bf16* A_t  = (__bf16*)(ws + W_F32_BYTES + B_F32_BYTES + W_BF16_BYTES);

    hipMemsetAsync(Wf_t, 0, W_F32_BYTES + B_F32_BYTES, stream);

    dim3 bxg(MBLKS, 17);
    build_xt_kernel<<<bxg, 256, 0, stream>>>(x, e0v, e0p, e1v, e1p, A_t);

    scatter_kernel<<<(NNZ_W + NNZ_B + 255) / 256, 256, 0, stream>>>(
        w_vals, w_rows, w_cols, b_vals, b_idx, Wf_t, bf);

    w_to_bf16_kernel<<<((size_t)OUT_F * IN_TOT / 4) / 256, 256, 0, stream>>>(Wf_t, Wb_t);

    gemm_kernel<<<512, 256, 0, stream>>>(A_t, Wb_t, bf, out);
}